// Round 12
// baseline (386.713 us; speedup 1.0000x reference)
//
#include <hip/hip_runtime.h>

// ============================================================================
// TypeNet triplet embedder — Round 12: R7 best-known structure + deterministic
// partial-sum BN stats (R11) + split-accumulator MFMA chains (new).
//   prep_all: xpad (A-frag fp16 x), whhT1/whhT2 fp16 [k][g], b1c.
//   lstm1:    fp16 weight frags (coalesced-ish prologue), split-acc step loop,
//             hs1 out (A-frag), per-WG BN1 partials (plain stores).
//   mid:      reduce partials -> w2s (BN1-folded Wih2 fp16) + bias2eff.
//   lstm2:    whhT2/w2s fp16 frags, split-acc step loop, 2-deep hs1 prefetch,
//             hlast (A-frag), per-WG BN2 partials.
//   head:     reduce partials; BN2 + FC + L2-normalize.
//   Invariants: conflict-free A-frag LDS h layout, one lgkm-only BAR/step,
//   R3 lstm_cell, 512-thr monolithic waves, no ws memset (all ws bytes
//   written before read each launch).
//   Split-acc: post-barrier dependent-MFMA depth 4 -> 2 (+1 f32 add).
// ============================================================================

typedef __attribute__((ext_vector_type(8))) _Float16 half8;
typedef __attribute__((ext_vector_type(4))) float f32x4;

#define TS 128
#define HID 128
#define NGATE 512
#define INV_N (1.0f/65536.0f)   // 1/(B*T)

#define BAR() asm volatile("s_waitcnt lgkmcnt(0)\n\ts_barrier" ::: "memory")

__device__ __forceinline__ float rcpf(float x) { return __builtin_amdgcn_rcpf(x); }
__device__ __forceinline__ float clamp20(float x) { return fminf(fmaxf(x, -20.0f), 20.0f); }

// Fused LSTM gate elementwise (R3-proven): 5 exp + 3 rcp per element.
__device__ __forceinline__ _Float16 lstm_cell(float zi, float zf, float zg, float zo,
                                              float& c) {
  zg = clamp20(zg);
  float ei = __expf(-zi);
  float eg = __expf(-2.0f * zg);
  float ef = __expf(-zf);
  float fv = rcpf(1.0f + ef);
  float ig = (1.0f - eg) * rcpf((1.0f + ei) * (1.0f + eg));  // sigmoid(zi)*tanh(zg)
  float cc = fv * c + ig;
  c = cc;
  float ccl = clamp20(cc);
  float eo = __expf(-zo);
  float ec = __expf(-2.0f * ccl);
  float hv = (1.0f - ec) * rcpf((1.0f + eo) * (1.0f + ec));  // sigmoid(zo)*tanh(cc)
  return (_Float16)hv;
}

// A-frag layout for a 16x128 fp16 tile:
//   addr(row,col) = (col>>5)*512 + ((col>>3)&3)*128 + row*8 + (col&7)
// Reader lane (row=l15, k=kt*32+quad*8+j): base = kt*512 + (quad*16+l15)*8.

// ---------------------------------------------------------------------------
// Fused prep: xpad (A-frag fp16 x), whhT for both layers, combined bias1.
// ---------------------------------------------------------------------------
__global__ void prep_all(const float* __restrict__ xa, const float* __restrict__ xp,
                         const float* __restrict__ xn,
                         const float* __restrict__ Whh1, const float* __restrict__ Whh2,
                         const float* __restrict__ bih1, const float* __restrict__ bhh1,
                         _Float16* __restrict__ xpad,
                         _Float16* __restrict__ whhT1, _Float16* __restrict__ whhT2,
                         float* __restrict__ b1c) {
  int bid = blockIdx.x, tid = threadIdx.x;
  if (bid < 6144) {                      // xpad: [96 tile][128 t][16 r][8 d]
    int i = bid * 256 + tid;
    int tile = i >> 14, rem = i & 16383;
    int t = rem >> 7, r = (rem >> 3) & 15, d = i & 7;
    int inp = tile >> 5, rloc = (tile & 31) * 16;
    const float* x = (inp == 0) ? xa : ((inp == 1) ? xp : xn);
    xpad[i] = (d < 5) ? (_Float16)x[(rloc + r) * 640 + t * 5 + d] : (_Float16)0.0f;
  } else if (bid < 6656) {               // whhT: [128 k][512 g]
    int i = (bid - 6144) * 256 + tid;
    int which = i >> 16, idx = i & 65535;
    int k = idx >> 9, g = idx & 511;
    const float* src = which ? Whh2 : Whh1;
    (which ? whhT2 : whhT1)[idx] = (_Float16)src[g * HID + k];
  } else {                               // b1c
    int i = (bid - 6656) * 256 + tid;    // 512
    b1c[i] = bih1[i] + bhh1[i];
  }
}

// ---------------------------------------------------------------------------
// LSTM layer 1. 96 WGs x 512. hs1: [96 tile][128 t][2048] A-frag order.
// ---------------------------------------------------------------------------
__global__ __launch_bounds__(512, 2) void lstm1_kernel(
    const _Float16* __restrict__ xpad,   // [96][128][16][8]
    const float* __restrict__ Wih1,      // [512][5]
    const float* __restrict__ b1c,       // [512]
    const _Float16* __restrict__ whhT,   // [128 k][512 g]
    _Float16* __restrict__ hs1,
    float* __restrict__ s1part, float* __restrict__ s1qpart) {
  const int wg = blockIdx.x;             // tile 0..95
  const int tid = threadIdx.x;
  const int w = tid >> 6;
  const int lane = tid & 63;
  const int l15 = lane & 15;
  const int quad = lane >> 4;
  const int col = w * 16 + l15;
  const int kb = quad * 8;

  __shared__ _Float16 hb[2][2048];       // double-buffered h, A-frag order
  for (int i = tid; i < 4096; i += 512) ((_Float16*)hb)[i] = (_Float16)0.0f;

  half8 bh[4][4];                        // [kt][gate] from prepped fp16
#pragma unroll
  for (int kt = 0; kt < 4; ++kt)
#pragma unroll
    for (int gt = 0; gt < 4; ++gt) {
      int gcol = gt * 128 + col;
      half8 v;
#pragma unroll
      for (int j = 0; j < 8; ++j) v[j] = whhT[(kt * 32 + kb + j) * NGATE + gcol];
      bh[kt][gt] = v;
    }
  half8 bx[4];                           // Wih1 K=32-padded (quad0, j<5)
#pragma unroll
  for (int gt = 0; gt < 4; ++gt) {
    half8 v = {0, 0, 0, 0, 0, 0, 0, 0};
    if (quad == 0) {
#pragma unroll
      for (int j = 0; j < 5; ++j) v[j] = (_Float16)Wih1[(gt * 128 + col) * 5 + j];
    }
    bx[gt] = v;
  }
  f32x4 biasv[4];
#pragma unroll
  for (int gt = 0; gt < 4; ++gt) {
    float b = b1c[gt * 128 + col];
    biasv[gt][0] = b; biasv[gt][1] = b; biasv[gt][2] = b; biasv[gt][3] = b;
  }
  const f32x4 zero4 = {0, 0, 0, 0};

  const int rbase = (quad * 16 + l15) * 8;
  const int wbase = (w >> 1) * 512 + ((w & 1) * 2 + (l15 >> 3)) * 128 +
                    quad * 32 + (l15 & 7);
  _Float16* hs1w = hs1 + (size_t)wg * TS * 2048;

  float c[4] = {0, 0, 0, 0};
  float ssum = 0.0f, ssq = 0.0f;
  __syncthreads();                       // hb zero-init visible

  half8 xv = {0, 0, 0, 0, 0, 0, 0, 0};
  if (quad == 0) xv = *(const half8*)&xpad[((size_t)(wg * TS) * 16 + l15) * 8];

  for (int t = 0; t < TS; ++t) {
    // ---- pre-barrier: x-part (prefetched regs) ----
    f32x4 acc[4];
#pragma unroll
    for (int gt = 0; gt < 4; ++gt)
      acc[gt] = __builtin_amdgcn_mfma_f32_16x16x32_f16(xv, bx[gt], biasv[gt], 0, 0, 0);
    if (t + 1 < TS && quad == 0)
      xv = *(const half8*)&xpad[((size_t)(wg * TS + t + 1) * 16 + l15) * 8];
    BAR();                               // h(t-1) visible
    // ---- h-part: split accumulators (2-deep chains) ----
    half8 ah0 = *(const half8*)&hb[t & 1][0 * 512 + rbase];
    half8 ah1 = *(const half8*)&hb[t & 1][1 * 512 + rbase];
    half8 ah2 = *(const half8*)&hb[t & 1][2 * 512 + rbase];
    half8 ah3 = *(const half8*)&hb[t & 1][3 * 512 + rbase];
    f32x4 acc2[4];
#pragma unroll
    for (int gt = 0; gt < 4; ++gt)
      acc[gt] = __builtin_amdgcn_mfma_f32_16x16x32_f16(ah0, bh[0][gt], acc[gt], 0, 0, 0);
#pragma unroll
    for (int gt = 0; gt < 4; ++gt)
      acc2[gt] = __builtin_amdgcn_mfma_f32_16x16x32_f16(ah2, bh[2][gt], zero4, 0, 0, 0);
#pragma unroll
    for (int gt = 0; gt < 4; ++gt)
      acc[gt] = __builtin_amdgcn_mfma_f32_16x16x32_f16(ah1, bh[1][gt], acc[gt], 0, 0, 0);
#pragma unroll
    for (int gt = 0; gt < 4; ++gt)
      acc2[gt] = __builtin_amdgcn_mfma_f32_16x16x32_f16(ah3, bh[3][gt], acc2[gt], 0, 0, 0);
    if (t > 0) {                         // coalesced h(t-1) -> hs1 (off chain)
      float2 cp = *(const float2*)&hb[t & 1][tid * 4];
      *(float2*)&hs1w[(size_t)(t - 1) * 2048 + tid * 4] = cp;
    }
#pragma unroll
    for (int gt = 0; gt < 4; ++gt)
      acc[gt] += acc2[gt];
    const int wb = (t + 1) & 1;
#pragma unroll
    for (int r = 0; r < 4; ++r) {
      _Float16 hh = lstm_cell(acc[0][r], acc[1][r], acc[2][r], acc[3][r], c[r]);
      float hr = (float)hh;
      ssum += hr; ssq += hr * hr;
      hb[wb][wbase + r * 8] = hh;
    }
  }
  BAR();                                 // h(127) visible
  {
    float2 cp = *(const float2*)&hb[0][tid * 4];
    *(float2*)&hs1w[(size_t)(TS - 1) * 2048 + tid * 4] = cp;
  }
  float s = ssum, q = ssq;
  s += __shfl_xor(s, 16); s += __shfl_xor(s, 32);
  q += __shfl_xor(q, 16); q += __shfl_xor(q, 32);
  if (quad == 0) {                       // deterministic per-WG partials
    s1part[wg * HID + col] = s;
    s1qpart[wg * HID + col] = q;
  }
}

// ---------------------------------------------------------------------------
// Mid: reduce BN1 partials; w2s = scale-folded Wih2 (fp16); bias2eff.
// ---------------------------------------------------------------------------
__global__ void mid_kernel(const float* __restrict__ s1part, const float* __restrict__ s1qpart,
                           const float* __restrict__ g1, const float* __restrict__ b1,
                           const float* __restrict__ Wih2,
                           const float* __restrict__ bih2, const float* __restrict__ bhh2,
                           _Float16* __restrict__ w2s, float* __restrict__ bias2eff) {
  int bid = blockIdx.x, tid = threadIdx.x;
  if (bid < 768) {                       // w2s: [3][128 k][512 g]; one (inp,k)/block
    int i0 = bid * 256;
    int inp = i0 >> 16, k = (i0 & 65535) >> 9;
    __shared__ float red[65];
    if (tid < 32) {
      red[tid] = s1part[(inp * 32 + tid) * HID + k];
      red[32 + tid] = s1qpart[(inp * 32 + tid) * HID + k];
    }
    __syncthreads();
    if (tid == 0) {
      float sm = 0.0f, sq = 0.0f;
      for (int j = 0; j < 32; ++j) { sm += red[j]; sq += red[32 + j]; }
      float m = sm * INV_N;
      float v = sq * INV_N - m * m;
      red[64] = g1[k] * rsqrtf(v + 1e-5f);
    }
    __syncthreads();
    float sc = red[64];
    int i = i0 + tid, g = i & 511;
    w2s[i] = (_Float16)(sc * Wih2[g * HID + k]);
  } else {                               // bias2eff: [3][512]
    int i = (bid - 768) * 256 + tid;
    int inp = i >> 9, g = i & 511;
    __shared__ float sh[128];
    if (tid < 128) {
      float sm = 0.0f, sq = 0.0f;
      for (int j = 0; j < 32; ++j) {
        sm += s1part[(inp * 32 + j) * HID + tid];
        sq += s1qpart[(inp * 32 + j) * HID + tid];
      }
      float m = sm * INV_N;
      float v = sq * INV_N - m * m;
      float s = g1[tid] * rsqrtf(v + 1e-5f);
      sh[tid] = b1[tid] - m * s;
    }
    __syncthreads();
    float acc = bih2[g] + bhh2[g];
    for (int h = 0; h < HID; ++h) acc += sh[h] * Wih2[g * HID + h];
    bias2eff[i] = acc;
  }
}

// ---------------------------------------------------------------------------
// LSTM layer 2. whhT2/w2s fp16 frags; split-acc; 2-deep hs1 prefetch.
// ---------------------------------------------------------------------------
__global__ __launch_bounds__(512, 2) void lstm2_kernel(
    const _Float16* __restrict__ hs1,    // [96][128][2048] A-frag order
    const _Float16* __restrict__ whhT2,  // [128 k][512 g]
    const _Float16* __restrict__ w2s,    // [3][128 k][512 g]
    const float* __restrict__ bias2eff,  // [3][512]
    _Float16* __restrict__ hlast,        // [96][2048] A-frag order
    float* __restrict__ s2part, float* __restrict__ s2qpart) {
  const int wg = blockIdx.x;             // tile 0..95
  const int inp = wg >> 5;
  const int tid = threadIdx.x;
  const int w = tid >> 6;
  const int lane = tid & 63;
  const int l15 = lane & 15;
  const int quad = lane >> 4;
  const int col = w * 16 + l15;
  const int kb = quad * 8;

  __shared__ _Float16 hb[2][2048];
  for (int i = tid; i < 4096; i += 512) ((_Float16*)hb)[i] = (_Float16)0.0f;

  const _Float16* w2sI = w2s + (size_t)inp * HID * NGATE;
  half8 bh[4][4], bxw[4][4];
#pragma unroll
  for (int kt = 0; kt < 4; ++kt)
#pragma unroll
    for (int gt = 0; gt < 4; ++gt) {
      int gcol = gt * 128 + col;
      half8 vh, vx;
#pragma unroll
      for (int j = 0; j < 8; ++j) {
        vh[j] = whhT2[(kt * 32 + kb + j) * NGATE + gcol];
        vx[j] = w2sI[(kt * 32 + kb + j) * NGATE + gcol];
      }
      bh[kt][gt] = vh;
      bxw[kt][gt] = vx;
    }
  f32x4 biasv[4];
#pragma unroll
  for (int gt = 0; gt < 4; ++gt) {
    float b = bias2eff[inp * NGATE + gt * 128 + col];
    biasv[gt][0] = b; biasv[gt][1] = b; biasv[gt][2] = b; biasv[gt][3] = b;
  }
  const f32x4 zero4 = {0, 0, 0, 0};

  const int rbase = (quad * 16 + l15) * 8;
  const int wbase = (w >> 1) * 512 + ((w & 1) * 2 + (l15 >> 3)) * 128 +
                    quad * 32 + (l15 & 7);
  const _Float16* hg = hs1 + (size_t)wg * TS * 2048;

  half8 a2A[4], a2B[4];                  // 2-deep hs1 prefetch (coalesced 16B)
#pragma unroll
  for (int kt = 0; kt < 4; ++kt) {
    a2A[kt] = *(const half8*)&hg[kt * 512 + rbase];
    a2B[kt] = *(const half8*)&hg[(size_t)2048 + kt * 512 + rbase];
  }

  float c[4] = {0, 0, 0, 0};
  float ssum = 0.0f, ssq = 0.0f;

  __syncthreads();                       // hb zero-init visible

  auto step = [&](int t, half8 (&cur)[4]) {
    // ---- pre-barrier: x-part, two independent 2-deep chains ----
    f32x4 acc[4], acc2[4];
#pragma unroll
    for (int gt = 0; gt < 4; ++gt)
      acc[gt] = __builtin_amdgcn_mfma_f32_16x16x32_f16(cur[0], bxw[0][gt], biasv[gt], 0, 0, 0);
#pragma unroll
    for (int gt = 0; gt < 4; ++gt)
      acc2[gt] = __builtin_amdgcn_mfma_f32_16x16x32_f16(cur[2], bxw[2][gt], zero4, 0, 0, 0);
#pragma unroll
    for (int gt = 0; gt < 4; ++gt)
      acc[gt] = __builtin_amdgcn_mfma_f32_16x16x32_f16(cur[1], bxw[1][gt], acc[gt], 0, 0, 0);
#pragma unroll
    for (int gt = 0; gt < 4; ++gt)
      acc2[gt] = __builtin_amdgcn_mfma_f32_16x16x32_f16(cur[3], bxw[3][gt], acc2[gt], 0, 0, 0);
    if (t + 2 < TS) {                    // prefetch t+2 into regs just consumed
#pragma unroll
      for (int kt = 0; kt < 4; ++kt)
        cur[kt] = *(const half8*)&hg[(size_t)(t + 2) * 2048 + kt * 512 + rbase];
    }
    BAR();                               // h(t-1) visible; vmcnt untouched
    half8 ah0 = *(const half8*)&hb[t & 1][0 * 512 + rbase];
    half8 ah1 = *(const half8*)&hb[t & 1][1 * 512 + rbase];
    half8 ah2 = *(const half8*)&hb[t & 1][2 * 512 + rbase];
    half8 ah3 = *(const half8*)&hb[t & 1][3 * 512 + rbase];
#pragma unroll
    for (int gt = 0; gt < 4; ++gt)
      acc[gt] = __builtin_amdgcn_mfma_f32_16x16x32_f16(ah0, bh[0][gt], acc[gt], 0, 0, 0);
#pragma unroll
    for (int gt = 0; gt < 4; ++gt)
      acc2[gt] = __builtin_amdgcn_mfma_f32_16x16x32_f16(ah2, bh[2][gt], acc2[gt], 0, 0, 0);
#pragma unroll
    for (int gt = 0; gt < 4; ++gt)
      acc[gt] = __builtin_amdgcn_mfma_f32_16x16x32_f16(ah1, bh[1][gt], acc[gt], 0, 0, 0);
#pragma unroll
    for (int gt = 0; gt < 4; ++gt)
      acc2[gt] = __builtin_amdgcn_mfma_f32_16x16x32_f16(ah3, bh[3][gt], acc2[gt], 0, 0, 0);
#pragma unroll
    for (int gt = 0; gt < 4; ++gt)
      acc[gt] += acc2[gt];
    const int wb = (t + 1) & 1;
#pragma unroll
    for (int r = 0; r < 4; ++r) {
      _Float16 hh = lstm_cell(acc[0][r], acc[1][r], acc[2][r], acc[3][r], c[r]);
      float hr = (float)hh;
      ssum += hr; ssq += hr * hr;
      hb[wb][wbase + r * 8] = hh;        // h(127) lands in buffer 0
    }
  };

  for (int t = 0; t < TS; t += 2) {
    step(t, a2A);
    step(t + 1, a2B);
  }

  BAR();                                 // h(127) writes visible
  {
    float2 cp = *(const float2*)&hb[0][tid * 4];
    *(float2*)&hlast[(size_t)wg * 2048 + tid * 4] = cp;
  }
  float s = ssum, q = ssq;
  s += __shfl_xor(s, 16); s += __shfl_xor(s, 32);
  q += __shfl_xor(q, 16); q += __shfl_xor(q, 32);
  if (quad == 0) {                       // deterministic per-WG partials
    s2part[wg * HID + col] = s;
    s2qpart[wg * HID + col] = q;
  }
}

// ---------------------------------------------------------------------------
// Head: reduce BN2 partials; BN2 + FC + L2 normalize. 96 WGs x 256.
// ---------------------------------------------------------------------------
__global__ __launch_bounds__(256, 1) void head_kernel(
    const _Float16* __restrict__ hlast,  // [96][2048] A-frag order
    const float* __restrict__ s2part, const float* __restrict__ s2qpart,
    const float* __restrict__ g2, const float* __restrict__ b2,
    const float* __restrict__ fcW, const float* __restrict__ fcb,
    float* __restrict__ out) {
  const int wg = blockIdx.x;
  const int inp = wg >> 5;
  const int gr0 = wg * 16;
  const int tid = threadIdx.x;

  __shared__ float fcwT[128][132];       // fcwT[h][j] = fcW[j][h]
  __shared__ float bnh[16][132];
  __shared__ float s2[128], sh2[128];
  __shared__ float part[16][16];
  __shared__ float inv[16];

  if (tid < 128) {
    float sm = 0.0f, sq = 0.0f;
    for (int j = 0; j < 32; ++j) {
      sm += s2part[(inp * 32 + j) * HID + tid];
      sq += s2qpart[(inp * 32 + j) * HID + tid];
    }
    float m = sm * INV_N;
    float v = sq * INV_N - m * m;
    float s = g2[tid] * rsqrtf(v + 1e-5f);
    s2[tid] = s; sh2[tid] = b2[tid] - m * s;
  }
  for (int i = tid; i < 16384; i += 256) {
    int j = i >> 7, h = i & 127;
    fcwT[h][j] = fcW[i];
  }
  __syncthreads();
  {
    int row = tid >> 4, c0 = (tid & 15) * 8;
#pragma unroll
    for (int k = 0; k < 8; ++k) {
      int h = c0 + k;
      int ad = ((h >> 5) << 9) + (((h >> 3) & 3) << 7) + (row << 3) + (h & 7);
      bnh[row][h] = (float)hlast[(size_t)wg * 2048 + ad] * s2[h] + sh2[h];
    }
  }
  __syncthreads();
  const int row = tid >> 4, jl = tid & 15;
  float emb[8];
  float sq = 0.0f;
#pragma unroll
  for (int jj = 0; jj < 8; ++jj) {
    int j = jl + jj * 16;
    float acc = fcb[j];
    for (int h = 0; h < HID; ++h) acc += bnh[row][h] * fcwT[h][j];
    emb[jj] = acc; sq += acc * acc;
  }
  part[row][jl] = sq;
  __syncthreads();
  if (tid < 16) {
    float s = 0.0f;
    for (int k = 0; k < 16; ++k) s += part[tid][k];
    inv[tid] = 1.0f / fmaxf(sqrtf(s), 1e-12f);
  }
  __syncthreads();
#pragma unroll
  for (int jj = 0; jj < 8; ++jj)
    out[(size_t)(gr0 + row) * HID + jl + jj * 16] = emb[jj] * inv[row];
}

// ---------------------------------------------------------------------------
extern "C" void kernel_launch(void* const* d_in, const int* in_sizes, int n_in,
                              void* d_out, int out_size, void* d_ws, size_t ws_size,
                              hipStream_t stream) {
  const float* a    = (const float*)d_in[0];
  const float* p    = (const float*)d_in[1];
  const float* nn   = (const float*)d_in[2];
  const float* Wih1 = (const float*)d_in[3];
  const float* Whh1 = (const float*)d_in[4];
  const float* bih1 = (const float*)d_in[5];
  const float* bhh1 = (const float*)d_in[6];
  const float* g1   = (const float*)d_in[7];
  const float* b1   = (const float*)d_in[8];
  const float* Wih2 = (const float*)d_in[9];
  const float* Whh2 = (const float*)d_in[10];
  const float* bih2 = (const float*)d_in[11];
  const float* bhh2 = (const float*)d_in[12];
  const float* g2   = (const float*)d_in[13];
  const float* b2   = (const float*)d_in[14];
  const float* fcW  = (const float*)d_in[15];
  const float* fcb  = (const float*)d_in[16];

  char* ws = (char*)d_ws;
  float* s1part  = (float*)(ws + 0);           // 96*128 f32 = 49152B
  float* s1qpart = (float*)(ws + 49152);       // -> @98304
  float* s2part  = (float*)(ws + 98304);       // -> @147456
  float* s2qpart = (float*)(ws + 147456);      // -> @196608
  float* b1c      = (float*)(ws + 196608);     // 2048B -> @198656
  float* bias2eff = (float*)(ws + 198656);     // 6144B -> @204800
  _Float16* whhT1 = (_Float16*)(ws + 204800);  // 131072B -> @335872
  _Float16* whhT2 = (_Float16*)(ws + 335872);  // 131072B -> @466944
  _Float16* w2s   = (_Float16*)(ws + 466944);  // 393216B -> @860160
  _Float16* hlast = (_Float16*)(ws + 860160);  // 393216B -> @1253376
  _Float16* xpad  = (_Float16*)(ws + 1253376); // 3145728B -> @4399104
  _Float16* hs1   = (_Float16*)(ws + 4399104); // 50331648B -> ~54.7MB total

  // No memset: every workspace byte read in a launch is written earlier in
  // that same launch (harness re-poisons ws to 0xAA between launches).

  prep_all<<<6658, 256, 0, stream>>>(a, p, nn, Whh1, Whh2, bih1, bhh1,
                                     xpad, whhT1, whhT2, b1c);
  lstm1_kernel<<<96, 512, 0, stream>>>(xpad, Wih1, b1c, whhT1,
                                       hs1, s1part, s1qpart);
  mid_kernel<<<774, 256, 0, stream>>>(s1part, s1qpart, g1, b1, Wih2, bih2, bhh2,
                                      w2s, bias2eff);
  lstm2_kernel<<<96, 512, 0, stream>>>(hs1, whhT2, w2s, bias2eff,
                                       hlast, s2part, s2qpart);
  head_kernel<<<96, 256, 0, stream>>>(hlast, s2part, s2qpart, g2, b2, fcW, fcb,
                                      (float*)d_out);
}